// Round 1
// baseline (2786.276 us; speedup 1.0000x reference)
//
#include <hip/hip_runtime.h>
#include <math.h>

#define B_SZ 128
#define N_OTH 2048
#define F_IMG 1024
#define F_TXT 512
#define D_EMB 512
#define NT 16   // n-rows per block in k_oth

// ws layout (floats):
//   [0, B*D)             img (normalized)
//   [B*D, B*D+B)         logit_in
//   [B*D+B, +B*N)        logits_oth

__global__ __launch_bounds__(512) void k_img(const float* __restrict__ in_img,
                                             const float* __restrict__ W,
                                             float* __restrict__ img) {
    const int b = blockIdx.x;
    const int d = threadIdx.x;
    __shared__ float row[F_IMG];
    __shared__ float wsum[8];
    __shared__ float s_rn;
    for (int i = d; i < F_IMG; i += 512) row[i] = in_img[b * F_IMG + i];
    __syncthreads();
    float acc = 0.f;
#pragma unroll 8
    for (int f = 0; f < F_IMG; ++f) acc = fmaf(row[f], W[f * D_EMB + d], acc);
    float sq = acc * acc;
#pragma unroll
    for (int off = 32; off > 0; off >>= 1) sq += __shfl_down(sq, off);
    const int lane = d & 63, wv = d >> 6;
    if (lane == 0) wsum[wv] = sq;
    __syncthreads();
    if (d == 0) {
        float s = 0.f;
        for (int w = 0; w < 8; ++w) s += wsum[w];
        s_rn = 1.0f / sqrtf(s);
    }
    __syncthreads();
    img[b * D_EMB + d] = acc * s_rn;
}

__global__ __launch_bounds__(512) void k_txt(const float* __restrict__ in_txt,
                                             const float* __restrict__ W,
                                             const float* __restrict__ img,
                                             const float* __restrict__ p_ls,
                                             float* __restrict__ logit_in) {
    const int b = blockIdx.x;
    const int d = threadIdx.x;
    __shared__ float row[F_TXT];
    __shared__ float wsum[8];
    __shared__ float s_rn;
    row[d] = in_txt[b * F_TXT + d];
    __syncthreads();
    float acc = 0.f;
#pragma unroll 8
    for (int f = 0; f < F_TXT; ++f) acc = fmaf(row[f], W[f * D_EMB + d], acc);
    float sq = acc * acc;
#pragma unroll
    for (int off = 32; off > 0; off >>= 1) sq += __shfl_down(sq, off);
    const int lane = d & 63, wv = d >> 6;
    if (lane == 0) wsum[wv] = sq;
    __syncthreads();
    if (d == 0) {
        float s = 0.f;
        for (int w = 0; w < 8; ++w) s += wsum[w];
        s_rn = 1.0f / sqrtf(s);
    }
    __syncthreads();
    const float t = acc * s_rn;
    float pd = t * img[b * D_EMB + d];
#pragma unroll
    for (int off = 32; off > 0; off >>= 1) pd += __shfl_down(pd, off);
    __syncthreads();  // before reusing wsum
    if (lane == 0) wsum[wv] = pd;
    __syncthreads();
    if (d == 0) {
        float s = 0.f;
        for (int w = 0; w < 8; ++w) s += wsum[w];
        logit_in[b] = expf(p_ls[0]) * s;
    }
}

__global__ __launch_bounds__(512) void k_oth(const float* __restrict__ oth,
                                             const float* __restrict__ W,
                                             const float* __restrict__ img,
                                             const float* __restrict__ p_ls,
                                             float* __restrict__ logits) {
    const int b = blockIdx.y;
    const int n0 = blockIdx.x * NT;
    const int tid = threadIdx.x;  // = d column
    __shared__ float sT[NT * F_TXT];  // 32 KB

    const float* src = oth + ((size_t)b * N_OTH + n0) * F_TXT;
    // vectorized stage: NT*512/4 = 2048 float4
    for (int i = tid; i < NT * F_TXT / 4; i += 512)
        reinterpret_cast<float4*>(sT)[i] = reinterpret_cast<const float4*>(src)[i];
    __syncthreads();

    const float img_d = img[b * D_EMB + tid];
    float acc[NT];
#pragma unroll
    for (int n = 0; n < NT; ++n) acc[n] = 0.f;

    for (int f0 = 0; f0 < F_TXT; f0 += 4) {
        const float w0 = W[(f0 + 0) * D_EMB + tid];
        const float w1 = W[(f0 + 1) * D_EMB + tid];
        const float w2 = W[(f0 + 2) * D_EMB + tid];
        const float w3 = W[(f0 + 3) * D_EMB + tid];
#pragma unroll
        for (int n = 0; n < NT; ++n) {
            const float4 t4 = *reinterpret_cast<const float4*>(&sT[n * F_TXT + f0]);
            acc[n] = fmaf(t4.x, w0, acc[n]);
            acc[n] = fmaf(t4.y, w1, acc[n]);
            acc[n] = fmaf(t4.z, w2, acc[n]);
            acc[n] = fmaf(t4.w, w3, acc[n]);
        }
    }

    const int lane = tid & 63, wv = tid >> 6;
    __syncthreads();  // done reading sT, reuse as reduction scratch
    float* red = sT;  // [NT][8] num then [NT][8] den
#pragma unroll
    for (int n = 0; n < NT; ++n) {
        float nu = img_d * acc[n];
        float de = acc[n] * acc[n];
#pragma unroll
        for (int off = 32; off > 0; off >>= 1) {
            nu += __shfl_down(nu, off);
            de += __shfl_down(de, off);
        }
        if (lane == 0) {
            red[n * 8 + wv] = nu;
            red[NT * 8 + n * 8 + wv] = de;
        }
    }
    __syncthreads();
    if (tid < NT) {
        float nu = 0.f, de = 0.f;
        for (int w = 0; w < 8; ++w) {
            nu += red[tid * 8 + w];
            de += red[NT * 8 + tid * 8 + w];
        }
        const float scale = expf(p_ls[0]);
        logits[(size_t)b * N_OTH + n0 + tid] = scale * nu / sqrtf(de);
    }
}

__global__ __launch_bounds__(256) void k_topk(const float* __restrict__ logits,
                                              const float* __restrict__ logit_in,
                                              float* __restrict__ out) {
    const int b = blockIdx.x;
    const int tid = threadIdx.x;
    __shared__ float a[N_OTH];  // 8 KB
    for (int i = tid; i < N_OTH; i += 256) a[i] = logits[(size_t)b * N_OTH + i];
    __syncthreads();
    // bitonic full sort, ascending
    for (unsigned k = 2; k <= N_OTH; k <<= 1) {
        for (unsigned j = k >> 1; j > 0; j >>= 1) {
            for (int s = 0; s < N_OTH / 256; ++s) {
                const unsigned i = tid + s * 256u;
                const unsigned ixj = i ^ j;
                if (ixj > i) {
                    const bool asc = ((i & k) == 0);
                    const float x = a[i], y = a[ixj];
                    if ((x > y) == asc) { a[i] = y; a[ixj] = x; }
                }
            }
            __syncthreads();
        }
    }
    // descending m-th = a[N-1-m]; out[b][j]: j==b -> logit_in, else sorted[j-(j>b)]
    if (tid < 128) {
        const int j = tid;
        float v;
        if (j == b) {
            v = logit_in[b];
        } else {
            const int m = j - (j > b ? 1 : 0);
            v = a[N_OTH - 1 - m];
        }
        out[b * 128 + j] = v;
    }
}

extern "C" void kernel_launch(void* const* d_in, const int* in_sizes, int n_in,
                              void* d_out, int out_size, void* d_ws, size_t ws_size,
                              hipStream_t stream) {
    const float* in_img = (const float*)d_in[0];
    const float* in_txt = (const float*)d_in[1];
    const float* oth    = (const float*)d_in[2];
    const float* W_img  = (const float*)d_in[3];
    const float* W_txt  = (const float*)d_in[4];
    const float* p_ls   = (const float*)d_in[5];
    float* out = (float*)d_out;

    float* ws = (float*)d_ws;
    float* img      = ws;                        // B*D
    float* logit_in = ws + B_SZ * D_EMB;         // B
    float* logits   = ws + B_SZ * D_EMB + B_SZ;  // B*N

    k_img<<<B_SZ, 512, 0, stream>>>(in_img, W_img, img);
    k_txt<<<B_SZ, 512, 0, stream>>>(in_txt, W_txt, img, p_ls, logit_in);
    dim3 g3(N_OTH / NT, B_SZ);
    k_oth<<<g3, 512, 0, stream>>>(oth, W_txt, img, p_ls, logits);
    k_topk<<<B_SZ, 256, 0, stream>>>(logits, logit_in, out);
}

// Round 2
// 376.145 us; speedup vs baseline: 7.4074x; 7.4074x over previous
//
#include <hip/hip_runtime.h>
#include <math.h>

#define B_SZ 128
#define N_OTH 2048
#define F_IMG 1024
#define F_TXT 512
#define D_EMB 512

typedef __attribute__((ext_vector_type(8))) short short8;   // bf16x8 MFMA frag
typedef __attribute__((ext_vector_type(4))) float f32x4;    // MFMA acc

static __device__ __forceinline__ ushort f2bf(float f) {
    union { float f; unsigned u; } v; v.f = f;
    unsigned u = v.u;
    return (ushort)((u + 0x7fffu + ((u >> 16) & 1u)) >> 16);  // RNE
}

// ---------------- image encoder: img = normalize(in_img @ W_img) ----------------
__global__ __launch_bounds__(512) void k_img(const float* __restrict__ in_img,
                                             const float* __restrict__ W,
                                             float* __restrict__ img) {
    const int b = blockIdx.x;
    const int d = threadIdx.x;
    __shared__ float row[F_IMG];
    __shared__ float wsum[8];
    __shared__ float s_rn;
    for (int i = d; i < F_IMG; i += 512) row[i] = in_img[b * F_IMG + i];
    __syncthreads();
    float acc = 0.f;
#pragma unroll 8
    for (int f = 0; f < F_IMG; ++f) acc = fmaf(row[f], W[f * D_EMB + d], acc);
    float sq = acc * acc;
#pragma unroll
    for (int off = 32; off > 0; off >>= 1) sq += __shfl_down(sq, off);
    const int lane = d & 63, wv = d >> 6;
    if (lane == 0) wsum[wv] = sq;
    __syncthreads();
    if (d == 0) {
        float s = 0.f;
        for (int w = 0; w < 8; ++w) s += wsum[w];
        s_rn = 1.0f / sqrtf(s);
    }
    __syncthreads();
    img[b * D_EMB + d] = acc * s_rn;
}

// ---------------- text encoder + positive logit ----------------
__global__ __launch_bounds__(512) void k_txt(const float* __restrict__ in_txt,
                                             const float* __restrict__ W,
                                             const float* __restrict__ img,
                                             const float* __restrict__ p_ls,
                                             float* __restrict__ logit_in) {
    const int b = blockIdx.x;
    const int d = threadIdx.x;
    __shared__ float row[F_TXT];
    __shared__ float wsum[8];
    __shared__ float s_rn;
    row[d] = in_txt[b * F_TXT + d];
    __syncthreads();
    float acc = 0.f;
#pragma unroll 8
    for (int f = 0; f < F_TXT; ++f) acc = fmaf(row[f], W[f * D_EMB + d], acc);
    float sq = acc * acc;
#pragma unroll
    for (int off = 32; off > 0; off >>= 1) sq += __shfl_down(sq, off);
    const int lane = d & 63, wv = d >> 6;
    if (lane == 0) wsum[wv] = sq;
    __syncthreads();
    if (d == 0) {
        float s = 0.f;
        for (int w = 0; w < 8; ++w) s += wsum[w];
        s_rn = 1.0f / sqrtf(s);
    }
    __syncthreads();
    const float t = acc * s_rn;
    float pd = t * img[b * D_EMB + d];
#pragma unroll
    for (int off = 32; off > 0; off >>= 1) pd += __shfl_down(pd, off);
    __syncthreads();
    if (lane == 0) wsum[wv] = pd;
    __syncthreads();
    if (d == 0) {
        float s = 0.f;
        for (int w = 0; w < 8; ++w) s += wsum[w];
        logit_in[b] = expf(p_ls[0]) * s;
    }
}

// ---------------- W_txt -> bf16 in MFMA B-fragment order ----------------
// Wfrag[(kstep*32 + coltile)*64 + lane][j] = bf16(W[kstep*32 + (lane>>4)*8 + j][coltile*16 + (lane&15)])
__global__ __launch_bounds__(256) void k_wprep(const float* __restrict__ W,
                                               ushort* __restrict__ wf) {
    const int g = blockIdx.x * 256 + threadIdx.x;   // 32768 threads
    const int lane = g & 63;
    const int frag = g >> 6;
    const int kstep = frag >> 5;
    const int ct = frag & 31;
    const int d = ct * 16 + (lane & 15);
    const int kb = kstep * 32 + (lane >> 4) * 8;
    short8 o;
#pragma unroll
    for (int j = 0; j < 8; ++j) o[j] = (short)f2bf(W[(kb + j) * D_EMB + d]);
    *(short8*)(wf + (size_t)g * 8) = o;
}

// ---------------- fused GEMM + num/den reduction ----------------
// Block: 64 rows of flattened oth[B*N][512], 8 waves x 64 cols, BK=32, K=512.
__global__ __launch_bounds__(512) void k_gemm(const float* __restrict__ oth,
                                              const ushort* __restrict__ wf,
                                              const float* __restrict__ img,
                                              float* __restrict__ numA,
                                              float* __restrict__ denA) {
    __shared__ ushort sA[2][64 * 32];   // 2 x 4 KB, XOR-swizzled
    __shared__ float redN[8][64];
    __shared__ float redD[8][64];
    const int tid = threadIdx.x;
    const int l = tid & 63;
    const int wv = tid >> 6;
    const int b = blockIdx.x >> 5;                 // 32 blocks per batch element
    const size_t row0 = (size_t)blockIdx.x * 64;

    // staging: thread -> (row, 4 consecutive k)
    const int srow = tid >> 3;
    const int sk4 = (tid & 7) * 4;
    const float* gsrc = oth + (row0 + srow) * F_TXT + sk4;
    const int swb = (srow * 64 + sk4 * 2) ^ ((srow & 7) << 4);   // byte offset in tile

    f32x4 acc[4][4];
#pragma unroll
    for (int m = 0; m < 4; ++m)
#pragma unroll
        for (int n = 0; n < 4; ++n) acc[m][n] = (f32x4){0.f, 0.f, 0.f, 0.f};

    // prologue: stage k-step 0
    {
        float4 v = *(const float4*)gsrc;
        ushort4 p;
        p.x = f2bf(v.x); p.y = f2bf(v.y); p.z = f2bf(v.z); p.w = f2bf(v.w);
        *(ushort4*)((char*)sA[0] + swb) = p;
    }
    __syncthreads();

    // A-fragment swizzled byte offsets (4 m-groups); row&7 == l&7
    int abase[4];
#pragma unroll
    for (int m = 0; m < 4; ++m)
        abase[m] = (((m * 16 + (l & 15)) * 64 + (l >> 4) * 16) ^ ((l & 7) << 4));

    float4 nv;
    for (int s = 0; s < 16; ++s) {
        const int cur = s & 1;
        if (s < 15) nv = *(const float4*)(gsrc + (s + 1) * 32);   // prefetch next A
        short8 bf[4];
#pragma unroll
        for (int n = 0; n < 4; ++n)
            bf[n] = *(const short8*)(wf + (((size_t)(s * 32 + wv * 4 + n)) * 64 + l) * 8);
        short8 af[4];
#pragma unroll
        for (int m = 0; m < 4; ++m)
            af[m] = *(const short8*)((const char*)sA[cur] + abase[m]);
#pragma unroll
        for (int m = 0; m < 4; ++m)
#pragma unroll
            for (int n = 0; n < 4; ++n)
                acc[m][n] = __builtin_amdgcn_mfma_f32_16x16x32_bf16(af[m], bf[n], acc[m][n], 0, 0, 0);
        __syncthreads();
        if (s < 15) {
            ushort4 p;
            p.x = f2bf(nv.x); p.y = f2bf(nv.y); p.z = f2bf(nv.z); p.w = f2bf(nv.w);
            *(ushort4*)((char*)sA[cur ^ 1] + swb) = p;
        }
        __syncthreads();
    }

    // epilogue: per-row num = sum_c P*img[c], den = sum_c P^2
    float icol[4];
#pragma unroll
    for (int n = 0; n < 4; ++n)
        icol[n] = img[b * D_EMB + wv * 64 + n * 16 + (l & 15)];
#pragma unroll
    for (int m = 0; m < 4; ++m) {
#pragma unroll
        for (int r = 0; r < 4; ++r) {
            float tn = 0.f, td = 0.f;
#pragma unroll
            for (int n = 0; n < 4; ++n) {
                float p = acc[m][n][r];
                tn = fmaf(p, icol[n], tn);
                td = fmaf(p, p, td);
            }
#pragma unroll
            for (int off = 1; off <= 8; off <<= 1) {
                tn += __shfl_xor(tn, off);
                td += __shfl_xor(td, off);
            }
            if ((l & 15) == 0) {
                const int row = m * 16 + (l >> 4) * 4 + r;
                redN[wv][row] = tn;
                redD[wv][row] = td;
            }
        }
    }
    __syncthreads();
    if (tid < 64) {
        float tn = 0.f, td = 0.f;
#pragma unroll
        for (int w = 0; w < 8; ++w) { tn += redN[w][tid]; td += redD[w][tid]; }
        numA[row0 + tid] = tn;
        denA[row0 + tid] = td;
    }
}

// ---------------- logits + full bitonic sort + output assembly ----------------
__global__ __launch_bounds__(256) void k_topk(const float* __restrict__ numA,
                                              const float* __restrict__ denA,
                                              const float* __restrict__ logit_in,
                                              const float* __restrict__ p_ls,
                                              float* __restrict__ out) {
    const int b = blockIdx.x;
    const int tid = threadIdx.x;
    const float scale = expf(p_ls[0]);
    __shared__ float a[N_OTH];
    for (int i = tid; i < N_OTH; i += 256) {
        const float nu = numA[(size_t)b * N_OTH + i];
        const float de = denA[(size_t)b * N_OTH + i];
        a[i] = scale * nu / sqrtf(de);
    }
    __syncthreads();
    for (unsigned k = 2; k <= N_OTH; k <<= 1) {
        for (unsigned j = k >> 1; j > 0; j >>= 1) {
            for (int s = 0; s < N_OTH / 256; ++s) {
                const unsigned i = tid + s * 256u;
                const unsigned ixj = i ^ j;
                if (ixj > i) {
                    const bool asc = ((i & k) == 0);
                    const float x = a[i], y = a[ixj];
                    if ((x > y) == asc) { a[i] = y; a[ixj] = x; }
                }
            }
            __syncthreads();
        }
    }
    if (tid < 128) {
        const int j = tid;
        float v;
        if (j == b) {
            v = logit_in[b];
        } else {
            const int m = j - (j > b ? 1 : 0);
            v = a[N_OTH - 1 - m];
        }
        out[b * 128 + j] = v;
    }
}

extern "C" void kernel_launch(void* const* d_in, const int* in_sizes, int n_in,
                              void* d_out, int out_size, void* d_ws, size_t ws_size,
                              hipStream_t stream) {
    const float* in_img = (const float*)d_in[0];
    const float* in_txt = (const float*)d_in[1];
    const float* oth    = (const float*)d_in[2];
    const float* W_img  = (const float*)d_in[3];
    const float* W_txt  = (const float*)d_in[4];
    const float* p_ls   = (const float*)d_in[5];
    float* out = (float*)d_out;

    float* ws = (float*)d_ws;
    float* img      = ws;                                  // 65536 floats
    float* logit_in = ws + 65536;                          // 128
    float* numA     = ws + 65536 + 128;                    // 262144
    float* denA     = numA + 262144;                       // 262144
    ushort* wfrag   = (ushort*)(denA + 262144);            // 262144 ushorts (512 KB)

    k_wprep<<<128, 256, 0, stream>>>(W_txt, wfrag);
    k_img<<<B_SZ, 512, 0, stream>>>(in_img, W_img, img);
    k_txt<<<B_SZ, 512, 0, stream>>>(in_txt, W_txt, img, p_ls, logit_in);
    k_gemm<<<(B_SZ * N_OTH) / 64, 512, 0, stream>>>(oth, wfrag, img, numA, denA);
    k_topk<<<B_SZ, 256, 0, stream>>>(numA, denA, logit_in, p_ls, out);
}